// Round 13
// baseline (290.410 us; speedup 1.0000x reference)
//
#include <hip/hip_runtime.h>
#include <hip/hip_bf16.h>

#define N_NODES 50000
#define N_EDGES 625000
#define IN_DIM  300
#define KPAD    320   // IN_DIM padded to multiple of 32
#define HID     128
#define NLAYERS 4

#define SB      256                            // scan block size
#define NCH     ((N_NODES + SB - 1) / SB)      // 196 chunks
#define NGR     ((N_NODES + 31) / 32)          // 1563 quant groups (32 nodes each)

typedef __hip_bfloat16 bf16;
typedef __attribute__((ext_vector_type(8))) short short8;   // 8 bf16 = 4 VGPRs
typedef __attribute__((ext_vector_type(4))) float f32x4;

__device__ inline short f2bf(float v) {
    bf16 t = __float2bfloat16(v);
    return *reinterpret_cast<short*>(&t);
}
__device__ inline unsigned short f2bfu(float v) {
    bf16 t = __float2bfloat16(v);
    return *reinterpret_cast<unsigned short*>(&t);
}
__device__ inline float bflo(unsigned v) { return __uint_as_float((v & 0xffffu) << 16); }
__device__ inline float bfhi(unsigned v) { return __uint_as_float(v & 0xffff0000u); }

// ---------------- degree histogram (int) ----------------
__global__ void k_deg(const int* __restrict__ dst, int* __restrict__ deg) {
    int e = blockIdx.x * blockDim.x + threadIdx.x;
    if (e < N_EDGES) atomicAdd(&deg[dst[e]], 1);
}

// ---------------- scan1: per-chunk sums ----------------
__global__ void k_scan1(const int* __restrict__ deg, int* __restrict__ bsum) {
    const int i = blockIdx.x * SB + threadIdx.x;
    int v = (i < N_NODES) ? deg[i] : 0;
#pragma unroll
    for (int off = 32; off > 0; off >>= 1) v += __shfl_down(v, off);
    __shared__ int wsum[SB / 64];
    if ((threadIdx.x & 63) == 0) wsum[threadIdx.x >> 6] = v;
    __syncthreads();
    if (threadIdx.x == 0) {
        int s = 0;
#pragma unroll
        for (int w = 0; w < SB / 64; w++) s += wsum[w];
        bsum[blockIdx.x] = s;
    }
}

// scan3: block-offset scan (replaces scan2) + within-chunk scan; deg -> invdeg in place
__global__ void k_scan3(int* __restrict__ degbuf, const int* __restrict__ bsum,
                        int* __restrict__ rowcur) {
    __shared__ int s[SB];
    __shared__ int bs[SB];
    const int b = blockIdx.x, t = threadIdx.x;

    int bv = (t < NCH) ? bsum[t] : 0;
    bs[t] = bv;
    __syncthreads();
    for (int off = 1; off < SB; off <<= 1) {
        int u = (t >= off) ? bs[t - off] : 0;
        __syncthreads();
        bs[t] += u;
        __syncthreads();
    }
    const int boff = (b == 0) ? 0 : bs[b - 1];

    const int i = b * SB + t;
    int v = (i < N_NODES) ? degbuf[i] : 0;
    s[t] = v;
    __syncthreads();
    for (int off = 1; off < SB; off <<= 1) {
        int u = (t >= off) ? s[t - off] : 0;
        __syncthreads();
        s[t] += u;
        __syncthreads();
    }
    if (i < N_NODES) {
        rowcur[i] = boff + s[t] - v;                     // exclusive prefix
        ((float*)degbuf)[i] = 1.0f / (float)max(v, 1);   // invdeg, in place
    }
}

// ---------------- CSR fill ----------------
__global__ void k_fill(const int* __restrict__ src, const int* __restrict__ dst,
                       int* __restrict__ rowcur, int* __restrict__ csr_src) {
    int e = blockIdx.x * blockDim.x + threadIdx.x;
    if (e < N_EDGES) {
        int d = dst[e];
        int pos = atomicAdd(&rowcur[d], 1);
        csr_src[pos] = src[e];
    }
}

// ---------------- weight prep: Wl/Wr -> W^T bf16, emb_W -> embT (fused) ----------------
__global__ void k_wprep(const float* __restrict__ Wl, const float* __restrict__ Wr,
                        const float* __restrict__ embW,
                        bf16* __restrict__ WlT, bf16* __restrict__ WrT,
                        bf16* __restrict__ embT) {
    int idx = blockIdx.x * 256 + threadIdx.x;
    const int total1 = NLAYERS * HID * HID;
    if (idx < total1) {
        int l = idx / (HID * HID);
        int rem = idx - l * HID * HID;
        int k = rem >> 7;
        int f = rem & 127;
        size_t o = (size_t)l * HID * HID + (size_t)f * HID + k;
        WlT[o] = __float2bfloat16(Wl[idx]);
        WrT[o] = __float2bfloat16(Wr[idx]);
        return;
    }
    int idx2 = idx - total1;
    if (idx2 < HID * KPAD) {
        int f = idx2 / KPAD, k = idx2 - f * KPAD;
        float v = (k < IN_DIM) ? embW[(size_t)k * HID + f] : 0.0f;
        embT[idx2] = __float2bfloat16(v);
    }
}

// ---------------- embedding via MFMA with LDS-staged embT (k < 256) ----------------
__global__ __launch_bounds__(512)
void k_embed_mfma(const float* __restrict__ x, const bf16* __restrict__ embT,
                  const float* __restrict__ b, bf16* __restrict__ h) {
    __shared__ bf16 emb_s[HID][256];   // 64 KB
    const int wid  = threadIdx.x >> 6;          // 0..7
    const int lane = threadIdx.x & 63;
    const int r0   = blockIdx.x * 128 + wid * 16;
    const int lrow = lane & 15;
    const int kgrp = lane >> 4;

    for (int id = threadIdx.x; id < HID * 32; id += 512) {
        const int row = id >> 5, ch = id & 31;
        const int sc  = ch ^ (row & 7);
        *reinterpret_cast<uint4*>(&emb_s[row][sc * 8]) =
            *reinterpret_cast<const uint4*>(embT + (size_t)row * KPAD + ch * 8);
    }
    __syncthreads();

    const int arow = min(r0 + lrow, N_NODES - 1);
    const float* xrow = x + (size_t)arow * IN_DIM;

    f32x4 acc[8];
#pragma unroll
    for (int c = 0; c < 8; c++) acc[c] = (f32x4){0.f, 0.f, 0.f, 0.f};

#pragma unroll
    for (int kk = 0; kk < 8; kk++) {            // k < 256: B from LDS
        const int k0 = kk * 32 + kgrp * 8;
        float4 f0 = *reinterpret_cast<const float4*>(xrow + k0);
        float4 f1 = *reinterpret_cast<const float4*>(xrow + k0 + 4);
        short8 a;
        a[0] = f2bf(f0.x); a[1] = f2bf(f0.y); a[2] = f2bf(f0.z); a[3] = f2bf(f0.w);
        a[4] = f2bf(f1.x); a[5] = f2bf(f1.y); a[6] = f2bf(f1.z); a[7] = f2bf(f1.w);
#pragma unroll
        for (int c = 0; c < 8; c++) {
            const int row = c * 16 + lrow;
            const int kc  = (kk * 4 + kgrp) ^ (row & 7);
            short8 bfrag = *reinterpret_cast<const short8*>(&emb_s[row][kc * 8]);
            acc[c] = __builtin_amdgcn_mfma_f32_16x16x32_bf16(a, bfrag, acc[c], 0, 0, 0);
        }
    }
    {   // kk = 8: k in [256,288), all valid; B from global
        const int k0 = 256 + kgrp * 8;
        float4 f0 = *reinterpret_cast<const float4*>(xrow + k0);
        float4 f1 = *reinterpret_cast<const float4*>(xrow + k0 + 4);
        short8 a;
        a[0] = f2bf(f0.x); a[1] = f2bf(f0.y); a[2] = f2bf(f0.z); a[3] = f2bf(f0.w);
        a[4] = f2bf(f1.x); a[5] = f2bf(f1.y); a[6] = f2bf(f1.z); a[7] = f2bf(f1.w);
#pragma unroll
        for (int c = 0; c < 8; c++) {
            short8 bfrag = *reinterpret_cast<const short8*>(embT + (size_t)(c * 16 + lrow) * KPAD + k0);
            acc[c] = __builtin_amdgcn_mfma_f32_16x16x32_bf16(a, bfrag, acc[c], 0, 0, 0);
        }
    }
    {   // kk = 9: k in [288,320), mask k >= 300; B from global (zero-padded)
        const int k0 = 288 + kgrp * 8;
        short8 a;
#pragma unroll
        for (int j = 0; j < 8; j++) {
            int k = k0 + j;
            a[j] = f2bf((k < IN_DIM) ? xrow[k] : 0.0f);
        }
#pragma unroll
        for (int c = 0; c < 8; c++) {
            short8 bfrag = *reinterpret_cast<const short8*>(embT + (size_t)(c * 16 + lrow) * KPAD + k0);
            acc[c] = __builtin_amdgcn_mfma_f32_16x16x32_bf16(a, bfrag, acc[c], 0, 0, 0);
        }
    }

#pragma unroll
    for (int c = 0; c < 8; c++) {
        const int col = c * 16 + lrow;
        const float bias = b[col];
#pragma unroll
        for (int r = 0; r < 4; r++) {
            const int row = r0 + kgrp * 4 + r;
            if (row < N_NODES)
                h[(size_t)row * HID + col] = __float2bfloat16(fmaxf(acc[c][r] + bias, 0.0f));
        }
    }
}

// ---------------- quantize h -> u8 with per-32-node-group scale ----------------
// one block per group: 32 nodes x 128 cols = 4096 bf16; 256 thr x 16 values.
// h >= 0 (relu). q = rint(v * 255/gmax); gscale[b] = gmax/255.
__global__ void k_quant(const bf16* __restrict__ h, unsigned char* __restrict__ q8,
                        float* __restrict__ gscale) {
    __shared__ float redm[256];
    const int b = blockIdx.x;
    const int t = threadIdx.x;
    const int nvalid = (min(N_NODES - b * 32, 32)) * HID;   // multiple of 128
    const size_t base = (size_t)b * 32 * HID + (size_t)t * 16;
    const bool act = t * 16 < nvalid;

    float f[16];
    if (act) {
        uint4 w0 = *reinterpret_cast<const uint4*>(h + base);
        uint4 w1 = *reinterpret_cast<const uint4*>(h + base + 8);
        unsigned wv[8] = {w0.x, w0.y, w0.z, w0.w, w1.x, w1.y, w1.z, w1.w};
#pragma unroll
        for (int j = 0; j < 8; j++) { f[2*j] = bflo(wv[j]); f[2*j+1] = bfhi(wv[j]); }
    } else {
#pragma unroll
        for (int j = 0; j < 16; j++) f[j] = 0.0f;
    }
    float m = 0.0f;
#pragma unroll
    for (int j = 0; j < 16; j++) m = fmaxf(m, f[j]);
    redm[t] = m;
    __syncthreads();
    for (int off = 128; off > 0; off >>= 1) {
        if (t < off) redm[t] = fmaxf(redm[t], redm[t + off]);
        __syncthreads();
    }
    const float gmax = redm[0];
    if (t == 0) gscale[b] = gmax * (1.0f / 255.0f);
    if (!act) return;
    const float inv = (gmax > 0.0f) ? (255.0f / gmax) : 0.0f;
    uint4 o;
    unsigned ow[4];
#pragma unroll
    for (int w = 0; w < 4; w++) {
        unsigned b0 = (unsigned)rintf(f[4*w+0] * inv);
        unsigned b1 = (unsigned)rintf(f[4*w+1] * inv);
        unsigned b2 = (unsigned)rintf(f[4*w+2] * inv);
        unsigned b3 = (unsigned)rintf(f[4*w+3] * inv);
        ow[w] = b0 | (b1 << 8) | (b2 << 16) | (b3 << 24);
    }
    o.x = ow[0]; o.y = ow[1]; o.z = ow[2]; o.w = ow[3];
    *reinterpret_cast<uint4*>(q8 + base) = o;
}

// ---------------- gather-aggregate over u8 rows: eighth-wave per edge, 16B/lane ----
// one wave per node; g = lane>>3 owns edge stream, fl = lane&7 owns 16 bytes (cols fl*16..+15).
// one uint4 row-load instruction covers 8 edges' row-chunks (8 rows x 128B).
__global__ void k_gather(const int* __restrict__ rowend, const int* __restrict__ csr_src,
                         const unsigned char* __restrict__ q8, const float* __restrict__ gscale,
                         const float* __restrict__ invdeg, bf16* __restrict__ agg) {
    const int node = blockIdx.x * (blockDim.x >> 6) + (threadIdx.x >> 6);
    if (node >= N_NODES) return;
    const int lane = threadIdx.x & 63;
    const int g    = lane >> 3;          // 0..7
    const int fl   = lane & 7;           // 0..7
    const int beg = (node == 0) ? 0 : rowend[node - 1];
    const int end = rowend[node];

    float acc[16];
#pragma unroll
    for (int j = 0; j < 16; j++) acc[j] = 0.0f;

#define DQ(vv, sc) { \
        unsigned wv_[4] = {vv.x, vv.y, vv.z, vv.w}; \
        _Pragma("unroll") \
        for (int w_ = 0; w_ < 4; w_++) { \
            acc[4*w_+0] = fmaf((float)(wv_[w_] & 255u),        sc, acc[4*w_+0]); \
            acc[4*w_+1] = fmaf((float)((wv_[w_] >> 8) & 255u), sc, acc[4*w_+1]); \
            acc[4*w_+2] = fmaf((float)((wv_[w_] >> 16) & 255u),sc, acc[4*w_+2]); \
            acc[4*w_+3] = fmaf((float)(wv_[w_] >> 24),         sc, acc[4*w_+3]); \
        } }

    int e = beg;
    for (; e + 16 <= end; e += 16) {     // 16 edges, 6 VMEM instrs
        int s0 = csr_src[e + g];
        int s1 = csr_src[e + 8 + g];
        float sc0 = gscale[s0 >> 5];
        float sc1 = gscale[s1 >> 5];
        uint4 v0 = *reinterpret_cast<const uint4*>(q8 + (size_t)s0 * HID + fl * 16);
        uint4 v1 = *reinterpret_cast<const uint4*>(q8 + (size_t)s1 * HID + fl * 16);
        DQ(v0, sc0);
        DQ(v1, sc1);
    }
    for (; e + 8 <= end; e += 8) {
        int s0 = csr_src[e + g];
        float sc0 = gscale[s0 >> 5];
        uint4 v0 = *reinterpret_cast<const uint4*>(q8 + (size_t)s0 * HID + fl * 16);
        DQ(v0, sc0);
    }
    if (e < end) {                       // tail: 1..7 edges, per-group predicated
        int idx = e + g;
        bool valid = idx < end;
        int s = csr_src[valid ? idx : end - 1];
        float sc = valid ? gscale[s >> 5] : 0.0f;
        uint4 v = *reinterpret_cast<const uint4*>(q8 + (size_t)s * HID + fl * 16);
        DQ(v, sc);
    }
#undef DQ

    // reduce across the 8 groups (lanes differing in bits 3,4,5)
#pragma unroll
    for (int j = 0; j < 16; j++) {
        acc[j] += __shfl_xor(acc[j], 8);
        acc[j] += __shfl_xor(acc[j], 16);
        acc[j] += __shfl_xor(acc[j], 32);
    }

    if (g == 0) {
        const float id = invdeg[node];
        uint4 o0, o1;
        unsigned ow[8];
#pragma unroll
        for (int w = 0; w < 8; w++)
            ow[w] = (unsigned)f2bfu(acc[2*w] * id) | ((unsigned)f2bfu(acc[2*w+1] * id) << 16);
        o0.x = ow[0]; o0.y = ow[1]; o0.z = ow[2]; o0.w = ow[3];
        o1.x = ow[4]; o1.y = ow[5]; o1.z = ow[6]; o1.w = ow[7];
        bf16* op = agg + (size_t)node * HID + fl * 16;
        *reinterpret_cast<uint4*>(op)     = o0;
        *reinterpret_cast<uint4*>(op + 8) = o1;
    }
}

// ---------------- combine via MFMA with LDS-staged weights ----------------
// h_out may alias agg: each wave reads only its own 16 rows before writing them.
template<int STORE_F32>
__global__ __launch_bounds__(512)
void k_combine_mfma(const bf16* __restrict__ agg, const bf16* __restrict__ h_in,
                    const bf16* __restrict__ WlT, const bf16* __restrict__ WrT,
                    const float* __restrict__ bl, void* __restrict__ outp) {
    __shared__ bf16 wl_s[HID][HID];   // 32 KB, swizzled chunks
    __shared__ bf16 wr_s[HID][HID];   // 32 KB
    const int wid  = threadIdx.x >> 6;          // 0..7
    const int lane = threadIdx.x & 63;
    const int r0   = blockIdx.x * 128 + wid * 16;
    const int lrow = lane & 15;
    const int kgrp = lane >> 4;

    for (int id = threadIdx.x; id < HID * 16; id += 512) {
        const int row = id >> 4, c16 = id & 15;
        const int sc  = c16 ^ (row & 7);
        *reinterpret_cast<uint4*>(&wl_s[row][sc * 8]) =
            *reinterpret_cast<const uint4*>(WlT + (size_t)row * HID + c16 * 8);
        *reinterpret_cast<uint4*>(&wr_s[row][sc * 8]) =
            *reinterpret_cast<const uint4*>(WrT + (size_t)row * HID + c16 * 8);
    }
    __syncthreads();

    f32x4 acc[8];
#pragma unroll
    for (int c = 0; c < 8; c++) acc[c] = (f32x4){0.f, 0.f, 0.f, 0.f};

    const int arow = min(r0 + lrow, N_NODES - 1);

#pragma unroll
    for (int kk = 0; kk < 4; kk++) {
        const int k0 = kk * 32 + kgrp * 8;
        short8 a = *reinterpret_cast<const short8*>(agg + (size_t)arow * HID + k0);
#pragma unroll
        for (int c = 0; c < 8; c++) {
            const int row = c * 16 + lrow;
            const int kc  = (kk * 4 + kgrp) ^ (lrow & 7);
            short8 b = *reinterpret_cast<const short8*>(&wl_s[row][kc * 8]);
            acc[c] = __builtin_amdgcn_mfma_f32_16x16x32_bf16(a, b, acc[c], 0, 0, 0);
        }
    }
#pragma unroll
    for (int kk = 0; kk < 4; kk++) {
        const int k0 = kk * 32 + kgrp * 8;
        short8 a = *reinterpret_cast<const short8*>(h_in + (size_t)arow * HID + k0);
#pragma unroll
        for (int c = 0; c < 8; c++) {
            const int row = c * 16 + lrow;
            const int kc  = (kk * 4 + kgrp) ^ (lrow & 7);
            short8 b = *reinterpret_cast<const short8*>(&wr_s[row][kc * 8]);
            acc[c] = __builtin_amdgcn_mfma_f32_16x16x32_bf16(a, b, acc[c], 0, 0, 0);
        }
    }

#pragma unroll
    for (int c = 0; c < 8; c++) {
        const int col = c * 16 + lrow;
        const float bias = bl[col];
#pragma unroll
        for (int r = 0; r < 4; r++) {
            const int row = r0 + kgrp * 4 + r;
            if (row < N_NODES) {
                float v = fmaxf(acc[c][r] + bias, 0.0f);
                if (STORE_F32)
                    ((float*)outp)[(size_t)row * HID + col] = v;
                else
                    ((bf16*)outp)[(size_t)row * HID + col] = __float2bfloat16(v);
            }
        }
    }
}

extern "C" void kernel_launch(void* const* d_in, const int* in_sizes, int n_in,
                              void* d_out, int out_size, void* d_ws, size_t ws_size,
                              hipStream_t stream) {
    const float* x     = (const float*)d_in[0];
    const int*   ei    = (const int*)d_in[1];
    const float* emb_W = (const float*)d_in[2];
    const float* emb_b = (const float*)d_in[3];
    const float* Wl    = (const float*)d_in[4];
    const float* bl    = (const float*)d_in[5];
    const float* Wr    = (const float*)d_in[6];

    const int* src = ei;
    const int* dst = ei + N_EDGES;

    // workspace layout
    char* ws = (char*)d_ws;
    size_t o = 0;
    int*  degbuf = (int*)(ws + o);  o += ((size_t)N_NODES * 4 + 255) & ~(size_t)255;
    int*  rowcur = (int*)(ws + o);  o += ((size_t)N_NODES * 4 + 255) & ~(size_t)255;
    int*  csrsrc = (int*)(ws + o);  o += ((size_t)N_EDGES * 4 + 255) & ~(size_t)255;
    int*  bsum   = (int*)(ws + o);  o += ((size_t)NCH * 4 + 255) & ~(size_t)255;
    bf16* WlT    = (bf16*)(ws + o); o += ((size_t)NLAYERS * HID * HID * 2 + 255) & ~(size_t)255;
    bf16* WrT    = (bf16*)(ws + o); o += ((size_t)NLAYERS * HID * HID * 2 + 255) & ~(size_t)255;
    bf16* embT   = (bf16*)(ws + o); o += ((size_t)HID * KPAD * 2 + 255) & ~(size_t)255;
    float* gscale = (float*)(ws + o); o += ((size_t)NGR * 4 + 255) & ~(size_t)255;
    unsigned char* q8 = (unsigned char*)(ws + o); o += ((size_t)NGR * 32 * HID + 255) & ~(size_t)255;
    bf16* bufA   = (bf16*)(ws + o); o += ((size_t)N_NODES * HID * 2 + 255) & ~(size_t)255;
    bf16* bufB   = (bf16*)(ws + o);

    // ---- build CSR ----
    hipMemsetAsync(degbuf, 0, (size_t)N_NODES * sizeof(int), stream);
    k_deg<<<(N_EDGES + 255) / 256, 256, 0, stream>>>(dst, degbuf);
    k_scan1<<<NCH, SB, 0, stream>>>(degbuf, bsum);
    k_scan3<<<NCH, SB, 0, stream>>>(degbuf, bsum, rowcur);
    const float* invdeg = (const float*)degbuf;
    k_fill<<<(N_EDGES + 255) / 256, 256, 0, stream>>>(src, dst, rowcur, csrsrc);
    // rowcur[n] is now the END offset of row n

    // ---- weight prep (fused) ----
    const int wtotal = NLAYERS * HID * HID + HID * KPAD;
    k_wprep<<<(wtotal + 255) / 256, 256, 0, stream>>>(Wl, Wr, emb_W, WlT, WrT, embT);

    // ---- h0 = relu(x @ emb_W + emb_b) -> bufA (bf16), via MFMA + LDS embT ----
    const int ngrid = (N_NODES + 3) / 4;      // 12500
    const int cgrid = (N_NODES + 127) / 128;  // 391
    k_embed_mfma<<<cgrid, 512, 0, stream>>>(x, embT, emb_b, bufA);

    for (int l = 0; l < NLAYERS; l++) {
        bf16* h_in = (l & 1) ? bufB : bufA;
        bf16* aggb = (l & 1) ? bufA : bufB;
        k_quant<<<NGR, 256, 0, stream>>>(h_in, q8, gscale);
        k_gather<<<ngrid, 256, 0, stream>>>(rowcur, csrsrc, q8, gscale, invdeg, aggb);
        const bf16* wlt = WlT + (size_t)l * HID * HID;
        const bf16* wrt = WrT + (size_t)l * HID * HID;
        const float* blp = bl + (size_t)l * HID;
        if (l == NLAYERS - 1)
            k_combine_mfma<1><<<cgrid, 512, 0, stream>>>(aggb, h_in, wlt, wrt, blp, d_out);
        else
            k_combine_mfma<0><<<cgrid, 512, 0, stream>>>(aggb, h_in, wlt, wrt, blp, aggb);
    }
}

// Round 14
// 273.256 us; speedup vs baseline: 1.0628x; 1.0628x over previous
//
#include <hip/hip_runtime.h>
#include <hip/hip_bf16.h>

#define N_NODES 50000
#define N_EDGES 625000
#define IN_DIM  300
#define KPAD    320   // IN_DIM padded to multiple of 32
#define HID     128
#define NLAYERS 4

#define SB      256                            // scan block size
#define NCH     ((N_NODES + SB - 1) / SB)      // 196 chunks

typedef __hip_bfloat16 bf16;
typedef __attribute__((ext_vector_type(8))) short short8;   // 8 bf16 = 4 VGPRs
typedef __attribute__((ext_vector_type(4))) float f32x4;

__device__ inline short f2bf(float v) {
    bf16 t = __float2bfloat16(v);
    return *reinterpret_cast<short*>(&t);
}
__device__ inline unsigned short f2bfu(float v) {
    bf16 t = __float2bfloat16(v);
    return *reinterpret_cast<unsigned short*>(&t);
}
__device__ inline float bflo(unsigned v) { return __uint_as_float((v & 0xffffu) << 16); }
__device__ inline float bfhi(unsigned v) { return __uint_as_float(v & 0xffff0000u); }

// ---------------- degree histogram (int) ----------------
__global__ void k_deg(const int* __restrict__ dst, int* __restrict__ deg) {
    int e = blockIdx.x * blockDim.x + threadIdx.x;
    if (e < N_EDGES) atomicAdd(&deg[dst[e]], 1);
}

// ---------------- scan1: per-chunk sums ----------------
__global__ void k_scan1(const int* __restrict__ deg, int* __restrict__ bsum) {
    const int i = blockIdx.x * SB + threadIdx.x;
    int v = (i < N_NODES) ? deg[i] : 0;
#pragma unroll
    for (int off = 32; off > 0; off >>= 1) v += __shfl_down(v, off);
    __shared__ int wsum[SB / 64];
    if ((threadIdx.x & 63) == 0) wsum[threadIdx.x >> 6] = v;
    __syncthreads();
    if (threadIdx.x == 0) {
        int s = 0;
#pragma unroll
        for (int w = 0; w < SB / 64; w++) s += wsum[w];
        bsum[blockIdx.x] = s;
    }
}

// scan3: block-offset scan (replaces scan2) + within-chunk scan; deg -> invdeg in place
__global__ void k_scan3(int* __restrict__ degbuf, const int* __restrict__ bsum,
                        int* __restrict__ rowcur) {
    __shared__ int s[SB];
    __shared__ int bs[SB];
    const int b = blockIdx.x, t = threadIdx.x;

    int bv = (t < NCH) ? bsum[t] : 0;
    bs[t] = bv;
    __syncthreads();
    for (int off = 1; off < SB; off <<= 1) {
        int u = (t >= off) ? bs[t - off] : 0;
        __syncthreads();
        bs[t] += u;
        __syncthreads();
    }
    const int boff = (b == 0) ? 0 : bs[b - 1];

    const int i = b * SB + t;
    int v = (i < N_NODES) ? degbuf[i] : 0;
    s[t] = v;
    __syncthreads();
    for (int off = 1; off < SB; off <<= 1) {
        int u = (t >= off) ? s[t - off] : 0;
        __syncthreads();
        s[t] += u;
        __syncthreads();
    }
    if (i < N_NODES) {
        rowcur[i] = boff + s[t] - v;                     // exclusive prefix
        ((float*)degbuf)[i] = 1.0f / (float)max(v, 1);   // invdeg, in place
    }
}

// ---------------- CSR fill ----------------
__global__ void k_fill(const int* __restrict__ src, const int* __restrict__ dst,
                       int* __restrict__ rowcur, int* __restrict__ csr_src) {
    int e = blockIdx.x * blockDim.x + threadIdx.x;
    if (e < N_EDGES) {
        int d = dst[e];
        int pos = atomicAdd(&rowcur[d], 1);
        csr_src[pos] = src[e];
    }
}

// ---------------- weight prep: Wl/Wr -> W^T bf16, emb_W -> embT (fused) ----------------
__global__ void k_wprep(const float* __restrict__ Wl, const float* __restrict__ Wr,
                        const float* __restrict__ embW,
                        bf16* __restrict__ WlT, bf16* __restrict__ WrT,
                        bf16* __restrict__ embT) {
    int idx = blockIdx.x * 256 + threadIdx.x;
    const int total1 = NLAYERS * HID * HID;
    if (idx < total1) {
        int l = idx / (HID * HID);
        int rem = idx - l * HID * HID;
        int k = rem >> 7;
        int f = rem & 127;
        size_t o = (size_t)l * HID * HID + (size_t)f * HID + k;
        WlT[o] = __float2bfloat16(Wl[idx]);
        WrT[o] = __float2bfloat16(Wr[idx]);
        return;
    }
    int idx2 = idx - total1;
    if (idx2 < HID * KPAD) {
        int f = idx2 / KPAD, k = idx2 - f * KPAD;
        float v = (k < IN_DIM) ? embW[(size_t)k * HID + f] : 0.0f;
        embT[idx2] = __float2bfloat16(v);
    }
}

// ---------------- embedding via MFMA; embT k<128 staged in 32 KB LDS ----------------
// 256 thr = 4 waves x 16 rows = 64 rows/block; grid 782; 32 KB LDS -> 5 blocks/CU (62% occ cap)
__global__ __launch_bounds__(256)
void k_embed_mfma(const float* __restrict__ x, const bf16* __restrict__ embT,
                  const float* __restrict__ b, bf16* __restrict__ h) {
    __shared__ bf16 emb_s[HID][HID];   // 32 KB: embT rows, k < 128, swizzled 16B chunks
    const int wid  = threadIdx.x >> 6;          // 0..3
    const int lane = threadIdx.x & 63;
    const int r0   = blockIdx.x * 64 + wid * 16;
    const int lrow = lane & 15;
    const int kgrp = lane >> 4;

    // stage embT[:, 0:128): 128 rows x 16 chunks of 16 B; chunk' = chunk ^ (row & 7)
    for (int id = threadIdx.x; id < HID * 16; id += 256) {
        const int row = id >> 4, ch = id & 15;
        const int sc  = ch ^ (row & 7);
        *reinterpret_cast<uint4*>(&emb_s[row][sc * 8]) =
            *reinterpret_cast<const uint4*>(embT + (size_t)row * KPAD + ch * 8);
    }
    __syncthreads();

    const int arow = min(r0 + lrow, N_NODES - 1);
    const float* xrow = x + (size_t)arow * IN_DIM;

    f32x4 acc[8];
#pragma unroll
    for (int c = 0; c < 8; c++) acc[c] = (f32x4){0.f, 0.f, 0.f, 0.f};

#pragma unroll
    for (int kk = 0; kk < 4; kk++) {            // k < 128: B from LDS
        const int k0 = kk * 32 + kgrp * 8;
        float4 f0 = *reinterpret_cast<const float4*>(xrow + k0);
        float4 f1 = *reinterpret_cast<const float4*>(xrow + k0 + 4);
        short8 a;
        a[0] = f2bf(f0.x); a[1] = f2bf(f0.y); a[2] = f2bf(f0.z); a[3] = f2bf(f0.w);
        a[4] = f2bf(f1.x); a[5] = f2bf(f1.y); a[6] = f2bf(f1.z); a[7] = f2bf(f1.w);
#pragma unroll
        for (int c = 0; c < 8; c++) {
            const int row = c * 16 + lrow;
            const int kc  = (kk * 4 + kgrp) ^ (row & 7);
            short8 bfrag = *reinterpret_cast<const short8*>(&emb_s[row][kc * 8]);
            acc[c] = __builtin_amdgcn_mfma_f32_16x16x32_bf16(a, bfrag, acc[c], 0, 0, 0);
        }
    }
#pragma unroll
    for (int kk = 4; kk < 9; kk++) {            // k in [128,288): B from global
        const int k0 = kk * 32 + kgrp * 8;
        float4 f0 = *reinterpret_cast<const float4*>(xrow + k0);
        float4 f1 = *reinterpret_cast<const float4*>(xrow + k0 + 4);
        short8 a;
        a[0] = f2bf(f0.x); a[1] = f2bf(f0.y); a[2] = f2bf(f0.z); a[3] = f2bf(f0.w);
        a[4] = f2bf(f1.x); a[5] = f2bf(f1.y); a[6] = f2bf(f1.z); a[7] = f2bf(f1.w);
#pragma unroll
        for (int c = 0; c < 8; c++) {
            short8 bfrag = *reinterpret_cast<const short8*>(embT + (size_t)(c * 16 + lrow) * KPAD + k0);
            acc[c] = __builtin_amdgcn_mfma_f32_16x16x32_bf16(a, bfrag, acc[c], 0, 0, 0);
        }
    }
    {   // kk = 9: k in [288,320), mask k >= 300; B from global (zero-padded)
        const int k0 = 288 + kgrp * 8;
        short8 a;
#pragma unroll
        for (int j = 0; j < 8; j++) {
            int k = k0 + j;
            a[j] = f2bf((k < IN_DIM) ? xrow[k] : 0.0f);
        }
#pragma unroll
        for (int c = 0; c < 8; c++) {
            short8 bfrag = *reinterpret_cast<const short8*>(embT + (size_t)(c * 16 + lrow) * KPAD + k0);
            acc[c] = __builtin_amdgcn_mfma_f32_16x16x32_bf16(a, bfrag, acc[c], 0, 0, 0);
        }
    }

#pragma unroll
    for (int c = 0; c < 8; c++) {
        const int col = c * 16 + lrow;
        const float bias = b[col];
#pragma unroll
        for (int r = 0; r < 4; r++) {
            const int row = r0 + kgrp * 4 + r;
            if (row < N_NODES)
                h[(size_t)row * HID + col] = __float2bfloat16(fmaxf(acc[c][r] + bias, 0.0f));
        }
    }
}

// ---------------- gather-aggregate: quarter-wave per edge, 16B/lane, 4-deep ----------------
__global__ void k_gather(const int* __restrict__ rowend, const int* __restrict__ csr_src,
                         const bf16* __restrict__ h, const float* __restrict__ invdeg,
                         bf16* __restrict__ agg) {
    const int node = blockIdx.x * (blockDim.x >> 6) + (threadIdx.x >> 6);
    if (node >= N_NODES) return;
    const int lane = threadIdx.x & 63;
    const int g    = lane >> 4;
    const int fl   = lane & 15;
    const int beg = (node == 0) ? 0 : rowend[node - 1];
    const int end = rowend[node];

    float a0 = 0.f, a1 = 0.f, a2 = 0.f, a3 = 0.f;
    float a4 = 0.f, a5 = 0.f, a6 = 0.f, a7 = 0.f;
    float c0 = 0.f, c1 = 0.f, c2 = 0.f, c3 = 0.f;
    float c4 = 0.f, c5 = 0.f, c6 = 0.f, c7 = 0.f;

    int e = beg;
    for (; e + 16 <= end; e += 16) {        // 16 edges in flight per wave
        int s0 = csr_src[e + g];
        int s1 = csr_src[e + 4 + g];
        int s2 = csr_src[e + 8 + g];
        int s3 = csr_src[e + 12 + g];
        uint4 v0 = *reinterpret_cast<const uint4*>(h + (size_t)s0 * HID + fl * 8);
        uint4 v1 = *reinterpret_cast<const uint4*>(h + (size_t)s1 * HID + fl * 8);
        uint4 v2 = *reinterpret_cast<const uint4*>(h + (size_t)s2 * HID + fl * 8);
        uint4 v3 = *reinterpret_cast<const uint4*>(h + (size_t)s3 * HID + fl * 8);
        a0 += bflo(v0.x); a1 += bfhi(v0.x); a2 += bflo(v0.y); a3 += bfhi(v0.y);
        a4 += bflo(v0.z); a5 += bfhi(v0.z); a6 += bflo(v0.w); a7 += bfhi(v0.w);
        c0 += bflo(v1.x); c1 += bfhi(v1.x); c2 += bflo(v1.y); c3 += bfhi(v1.y);
        c4 += bflo(v1.z); c5 += bfhi(v1.z); c6 += bflo(v1.w); c7 += bfhi(v1.w);
        a0 += bflo(v2.x); a1 += bfhi(v2.x); a2 += bflo(v2.y); a3 += bfhi(v2.y);
        a4 += bflo(v2.z); a5 += bfhi(v2.z); a6 += bflo(v2.w); a7 += bfhi(v2.w);
        c0 += bflo(v3.x); c1 += bfhi(v3.x); c2 += bflo(v3.y); c3 += bfhi(v3.y);
        c4 += bflo(v3.z); c5 += bfhi(v3.z); c6 += bflo(v3.w); c7 += bfhi(v3.w);
    }
    for (; e + 8 <= end; e += 8) {
        int s0 = csr_src[e + g];
        int s1 = csr_src[e + 4 + g];
        uint4 v0 = *reinterpret_cast<const uint4*>(h + (size_t)s0 * HID + fl * 8);
        uint4 v1 = *reinterpret_cast<const uint4*>(h + (size_t)s1 * HID + fl * 8);
        a0 += bflo(v0.x); a1 += bfhi(v0.x); a2 += bflo(v0.y); a3 += bfhi(v0.y);
        a4 += bflo(v0.z); a5 += bfhi(v0.z); a6 += bflo(v0.w); a7 += bfhi(v0.w);
        c0 += bflo(v1.x); c1 += bfhi(v1.x); c2 += bflo(v1.y); c3 += bfhi(v1.y);
        c4 += bflo(v1.z); c5 += bfhi(v1.z); c6 += bflo(v1.w); c7 += bfhi(v1.w);
    }
    for (; e + 4 <= end; e += 4) {
        int s0 = csr_src[e + g];
        uint4 v0 = *reinterpret_cast<const uint4*>(h + (size_t)s0 * HID + fl * 8);
        a0 += bflo(v0.x); a1 += bfhi(v0.x); a2 += bflo(v0.y); a3 += bfhi(v0.y);
        a4 += bflo(v0.z); a5 += bfhi(v0.z); a6 += bflo(v0.w); a7 += bfhi(v0.w);
    }
    if (e < end) {                           // tail: 1..3 edges, per-group predicated
        int idx = e + g;
        bool valid = idx < end;
        int s = csr_src[valid ? idx : end - 1];
        uint4 v = *reinterpret_cast<const uint4*>(h + (size_t)s * HID + fl * 8);
        if (valid) {
            a0 += bflo(v.x); a1 += bfhi(v.x); a2 += bflo(v.y); a3 += bfhi(v.y);
            a4 += bflo(v.z); a5 += bfhi(v.z); a6 += bflo(v.w); a7 += bfhi(v.w);
        }
    }
    a0 += c0; a1 += c1; a2 += c2; a3 += c3;
    a4 += c4; a5 += c5; a6 += c6; a7 += c7;

    // reduce across the 4 groups (lanes differing in bits 4,5)
    a0 += __shfl_xor(a0, 16); a1 += __shfl_xor(a1, 16);
    a2 += __shfl_xor(a2, 16); a3 += __shfl_xor(a3, 16);
    a4 += __shfl_xor(a4, 16); a5 += __shfl_xor(a5, 16);
    a6 += __shfl_xor(a6, 16); a7 += __shfl_xor(a7, 16);
    a0 += __shfl_xor(a0, 32); a1 += __shfl_xor(a1, 32);
    a2 += __shfl_xor(a2, 32); a3 += __shfl_xor(a3, 32);
    a4 += __shfl_xor(a4, 32); a5 += __shfl_xor(a5, 32);
    a6 += __shfl_xor(a6, 32); a7 += __shfl_xor(a7, 32);

    if (g == 0) {
        const float id = invdeg[node];
        uint4 o;
        o.x = (unsigned)f2bfu(a0 * id) | ((unsigned)f2bfu(a1 * id) << 16);
        o.y = (unsigned)f2bfu(a2 * id) | ((unsigned)f2bfu(a3 * id) << 16);
        o.z = (unsigned)f2bfu(a4 * id) | ((unsigned)f2bfu(a5 * id) << 16);
        o.w = (unsigned)f2bfu(a6 * id) | ((unsigned)f2bfu(a7 * id) << 16);
        *reinterpret_cast<uint4*>(agg + (size_t)node * HID + fl * 8) = o;
    }
}

// ---------------- combine via MFMA with LDS-staged weights ----------------
// h_out may alias agg: each wave reads only its own 16 rows before writing them.
template<int STORE_F32>
__global__ __launch_bounds__(512)
void k_combine_mfma(const bf16* __restrict__ agg, const bf16* __restrict__ h_in,
                    const bf16* __restrict__ WlT, const bf16* __restrict__ WrT,
                    const float* __restrict__ bl, void* __restrict__ outp) {
    __shared__ bf16 wl_s[HID][HID];   // 32 KB, swizzled chunks
    __shared__ bf16 wr_s[HID][HID];   // 32 KB
    const int wid  = threadIdx.x >> 6;          // 0..7
    const int lane = threadIdx.x & 63;
    const int r0   = blockIdx.x * 128 + wid * 16;
    const int lrow = lane & 15;
    const int kgrp = lane >> 4;

    for (int id = threadIdx.x; id < HID * 16; id += 512) {
        const int row = id >> 4, c16 = id & 15;
        const int sc  = c16 ^ (row & 7);
        *reinterpret_cast<uint4*>(&wl_s[row][sc * 8]) =
            *reinterpret_cast<const uint4*>(WlT + (size_t)row * HID + c16 * 8);
        *reinterpret_cast<uint4*>(&wr_s[row][sc * 8]) =
            *reinterpret_cast<const uint4*>(WrT + (size_t)row * HID + c16 * 8);
    }
    __syncthreads();

    f32x4 acc[8];
#pragma unroll
    for (int c = 0; c < 8; c++) acc[c] = (f32x4){0.f, 0.f, 0.f, 0.f};

    const int arow = min(r0 + lrow, N_NODES - 1);

#pragma unroll
    for (int kk = 0; kk < 4; kk++) {
        const int k0 = kk * 32 + kgrp * 8;
        short8 a = *reinterpret_cast<const short8*>(agg + (size_t)arow * HID + k0);
#pragma unroll
        for (int c = 0; c < 8; c++) {
            const int row = c * 16 + lrow;
            const int kc  = (kk * 4 + kgrp) ^ (lrow & 7);
            short8 b = *reinterpret_cast<const short8*>(&wl_s[row][kc * 8]);
            acc[c] = __builtin_amdgcn_mfma_f32_16x16x32_bf16(a, b, acc[c], 0, 0, 0);
        }
    }
#pragma unroll
    for (int kk = 0; kk < 4; kk++) {
        const int k0 = kk * 32 + kgrp * 8;
        short8 a = *reinterpret_cast<const short8*>(h_in + (size_t)arow * HID + k0);
#pragma unroll
        for (int c = 0; c < 8; c++) {
            const int row = c * 16 + lrow;
            const int kc  = (kk * 4 + kgrp) ^ (lrow & 7);
            short8 b = *reinterpret_cast<const short8*>(&wr_s[row][kc * 8]);
            acc[c] = __builtin_amdgcn_mfma_f32_16x16x32_bf16(a, b, acc[c], 0, 0, 0);
        }
    }

#pragma unroll
    for (int c = 0; c < 8; c++) {
        const int col = c * 16 + lrow;
        const float bias = bl[col];
#pragma unroll
        for (int r = 0; r < 4; r++) {
            const int row = r0 + kgrp * 4 + r;
            if (row < N_NODES) {
                float v = fmaxf(acc[c][r] + bias, 0.0f);
                if (STORE_F32)
                    ((float*)outp)[(size_t)row * HID + col] = v;
                else
                    ((bf16*)outp)[(size_t)row * HID + col] = __float2bfloat16(v);
            }
        }
    }
}

extern "C" void kernel_launch(void* const* d_in, const int* in_sizes, int n_in,
                              void* d_out, int out_size, void* d_ws, size_t ws_size,
                              hipStream_t stream) {
    const float* x     = (const float*)d_in[0];
    const int*   ei    = (const int*)d_in[1];
    const float* emb_W = (const float*)d_in[2];
    const float* emb_b = (const float*)d_in[3];
    const float* Wl    = (const float*)d_in[4];
    const float* bl    = (const float*)d_in[5];
    const float* Wr    = (const float*)d_in[6];

    const int* src = ei;
    const int* dst = ei + N_EDGES;

    // workspace layout
    char* ws = (char*)d_ws;
    size_t o = 0;
    int*  degbuf = (int*)(ws + o);  o += ((size_t)N_NODES * 4 + 255) & ~(size_t)255;
    int*  rowcur = (int*)(ws + o);  o += ((size_t)N_NODES * 4 + 255) & ~(size_t)255;
    int*  csrsrc = (int*)(ws + o);  o += ((size_t)N_EDGES * 4 + 255) & ~(size_t)255;
    int*  bsum   = (int*)(ws + o);  o += ((size_t)NCH * 4 + 255) & ~(size_t)255;
    bf16* WlT    = (bf16*)(ws + o); o += ((size_t)NLAYERS * HID * HID * 2 + 255) & ~(size_t)255;
    bf16* WrT    = (bf16*)(ws + o); o += ((size_t)NLAYERS * HID * HID * 2 + 255) & ~(size_t)255;
    bf16* embT   = (bf16*)(ws + o); o += ((size_t)HID * KPAD * 2 + 255) & ~(size_t)255;
    bf16* bufA   = (bf16*)(ws + o); o += ((size_t)N_NODES * HID * 2 + 255) & ~(size_t)255;
    bf16* bufB   = (bf16*)(ws + o);

    // ---- build CSR ----
    hipMemsetAsync(degbuf, 0, (size_t)N_NODES * sizeof(int), stream);
    k_deg<<<(N_EDGES + 255) / 256, 256, 0, stream>>>(dst, degbuf);
    k_scan1<<<NCH, SB, 0, stream>>>(degbuf, bsum);
    k_scan3<<<NCH, SB, 0, stream>>>(degbuf, bsum, rowcur);
    const float* invdeg = (const float*)degbuf;
    k_fill<<<(N_EDGES + 255) / 256, 256, 0, stream>>>(src, dst, rowcur, csrsrc);
    // rowcur[n] is now the END offset of row n

    // ---- weight prep (fused) ----
    const int wtotal = NLAYERS * HID * HID + HID * KPAD;
    k_wprep<<<(wtotal + 255) / 256, 256, 0, stream>>>(Wl, Wr, emb_W, WlT, WrT, embT);

    // ---- h0 = relu(x @ emb_W + emb_b) -> bufA (bf16), via MFMA + 32KB LDS embT ----
    const int egrid = (N_NODES + 63) / 64;    // 782
    const int ngrid = (N_NODES + 3) / 4;      // 12500
    const int cgrid = (N_NODES + 127) / 128;  // 391
    k_embed_mfma<<<egrid, 256, 0, stream>>>(x, embT, emb_b, bufA);

    for (int l = 0; l < NLAYERS; l++) {
        bf16* h_in = (l & 1) ? bufB : bufA;
        bf16* aggb = (l & 1) ? bufA : bufB;
        k_gather<<<ngrid, 256, 0, stream>>>(rowcur, csrsrc, h_in, invdeg, aggb);
        const bf16* wlt = WlT + (size_t)l * HID * HID;
        const bf16* wrt = WrT + (size_t)l * HID * HID;
        const float* blp = bl + (size_t)l * HID;
        if (l == NLAYERS - 1)
            k_combine_mfma<1><<<cgrid, 512, 0, stream>>>(aggb, h_in, wlt, wrt, blp, d_out);
        else
            k_combine_mfma<0><<<cgrid, 512, 0, stream>>>(aggb, h_in, wlt, wrt, blp, aggb);
    }
}

// Round 15
// 271.982 us; speedup vs baseline: 1.0678x; 1.0047x over previous
//
#include <hip/hip_runtime.h>
#include <hip/hip_bf16.h>

#define N_NODES 50000
#define N_EDGES 625000
#define IN_DIM  300
#define KPAD    320   // IN_DIM padded to multiple of 32
#define HID     128
#define NLAYERS 4

#define SB      256                            // scan block size
#define NCH     ((N_NODES + SB - 1) / SB)      // 196 chunks

typedef __hip_bfloat16 bf16;
typedef __attribute__((ext_vector_type(8))) short short8;   // 8 bf16 = 4 VGPRs
typedef __attribute__((ext_vector_type(4))) float f32x4;

__device__ inline short f2bf(float v) {
    bf16 t = __float2bfloat16(v);
    return *reinterpret_cast<short*>(&t);
}
__device__ inline unsigned short f2bfu(float v) {
    bf16 t = __float2bfloat16(v);
    return *reinterpret_cast<unsigned short*>(&t);
}
__device__ inline float bflo(unsigned v) { return __uint_as_float((v & 0xffffu) << 16); }
__device__ inline float bfhi(unsigned v) { return __uint_as_float(v & 0xffff0000u); }

// ---------------- degree histogram (int) ----------------
__global__ void k_deg(const int* __restrict__ dst, int* __restrict__ deg) {
    int e = blockIdx.x * blockDim.x + threadIdx.x;
    if (e < N_EDGES) atomicAdd(&deg[dst[e]], 1);
}

// ---------------- scan1: per-chunk sums ----------------
__global__ void k_scan1(const int* __restrict__ deg, int* __restrict__ bsum) {
    const int i = blockIdx.x * SB + threadIdx.x;
    int v = (i < N_NODES) ? deg[i] : 0;
#pragma unroll
    for (int off = 32; off > 0; off >>= 1) v += __shfl_down(v, off);
    __shared__ int wsum[SB / 64];
    if ((threadIdx.x & 63) == 0) wsum[threadIdx.x >> 6] = v;
    __syncthreads();
    if (threadIdx.x == 0) {
        int s = 0;
#pragma unroll
        for (int w = 0; w < SB / 64; w++) s += wsum[w];
        bsum[blockIdx.x] = s;
    }
}

// scan3: block-offset scan (replaces scan2) + within-chunk scan; deg -> invdeg in place
__global__ void k_scan3(int* __restrict__ degbuf, const int* __restrict__ bsum,
                        int* __restrict__ rowcur) {
    __shared__ int s[SB];
    __shared__ int bs[SB];
    const int b = blockIdx.x, t = threadIdx.x;

    int bv = (t < NCH) ? bsum[t] : 0;
    bs[t] = bv;
    __syncthreads();
    for (int off = 1; off < SB; off <<= 1) {
        int u = (t >= off) ? bs[t - off] : 0;
        __syncthreads();
        bs[t] += u;
        __syncthreads();
    }
    const int boff = (b == 0) ? 0 : bs[b - 1];

    const int i = b * SB + t;
    int v = (i < N_NODES) ? degbuf[i] : 0;
    s[t] = v;
    __syncthreads();
    for (int off = 1; off < SB; off <<= 1) {
        int u = (t >= off) ? s[t - off] : 0;
        __syncthreads();
        s[t] += u;
        __syncthreads();
    }
    if (i < N_NODES) {
        rowcur[i] = boff + s[t] - v;                     // exclusive prefix
        ((float*)degbuf)[i] = 1.0f / (float)max(v, 1);   // invdeg, in place
    }
}

// ---------------- CSR fill ----------------
__global__ void k_fill(const int* __restrict__ src, const int* __restrict__ dst,
                       int* __restrict__ rowcur, int* __restrict__ csr_src) {
    int e = blockIdx.x * blockDim.x + threadIdx.x;
    if (e < N_EDGES) {
        int d = dst[e];
        int pos = atomicAdd(&rowcur[d], 1);
        csr_src[pos] = src[e];
    }
}

// ---------------- weight prep: Wl/Wr -> W^T bf16, emb_W -> embT (fused) ----------------
__global__ void k_wprep(const float* __restrict__ Wl, const float* __restrict__ Wr,
                        const float* __restrict__ embW,
                        bf16* __restrict__ WlT, bf16* __restrict__ WrT,
                        bf16* __restrict__ embT) {
    int idx = blockIdx.x * 256 + threadIdx.x;
    const int total1 = NLAYERS * HID * HID;
    if (idx < total1) {
        int l = idx / (HID * HID);
        int rem = idx - l * HID * HID;
        int k = rem >> 7;
        int f = rem & 127;
        size_t o = (size_t)l * HID * HID + (size_t)f * HID + k;
        WlT[o] = __float2bfloat16(Wl[idx]);
        WrT[o] = __float2bfloat16(Wr[idx]);
        return;
    }
    int idx2 = idx - total1;
    if (idx2 < HID * KPAD) {
        int f = idx2 / KPAD, k = idx2 - f * KPAD;
        float v = (k < IN_DIM) ? embW[(size_t)k * HID + f] : 0.0f;
        embT[idx2] = __float2bfloat16(v);
    }
}

// ---------------- embedding via MFMA with LDS-staged embT (k < 256) ----------------
// 512 thr = 8 waves x 16 rows = 128 rows/block; grid 391; 64 KB LDS (round-11, 39 us)
__global__ __launch_bounds__(512)
void k_embed_mfma(const float* __restrict__ x, const bf16* __restrict__ embT,
                  const float* __restrict__ b, bf16* __restrict__ h) {
    __shared__ bf16 emb_s[HID][256];   // 64 KB
    const int wid  = threadIdx.x >> 6;          // 0..7
    const int lane = threadIdx.x & 63;
    const int r0   = blockIdx.x * 128 + wid * 16;
    const int lrow = lane & 15;
    const int kgrp = lane >> 4;

    for (int id = threadIdx.x; id < HID * 32; id += 512) {
        const int row = id >> 5, ch = id & 31;
        const int sc  = ch ^ (row & 7);
        *reinterpret_cast<uint4*>(&emb_s[row][sc * 8]) =
            *reinterpret_cast<const uint4*>(embT + (size_t)row * KPAD + ch * 8);
    }
    __syncthreads();

    const int arow = min(r0 + lrow, N_NODES - 1);
    const float* xrow = x + (size_t)arow * IN_DIM;

    f32x4 acc[8];
#pragma unroll
    for (int c = 0; c < 8; c++) acc[c] = (f32x4){0.f, 0.f, 0.f, 0.f};

#pragma unroll
    for (int kk = 0; kk < 8; kk++) {            // k < 256: B from LDS
        const int k0 = kk * 32 + kgrp * 8;
        float4 f0 = *reinterpret_cast<const float4*>(xrow + k0);
        float4 f1 = *reinterpret_cast<const float4*>(xrow + k0 + 4);
        short8 a;
        a[0] = f2bf(f0.x); a[1] = f2bf(f0.y); a[2] = f2bf(f0.z); a[3] = f2bf(f0.w);
        a[4] = f2bf(f1.x); a[5] = f2bf(f1.y); a[6] = f2bf(f1.z); a[7] = f2bf(f1.w);
#pragma unroll
        for (int c = 0; c < 8; c++) {
            const int row = c * 16 + lrow;
            const int kc  = (kk * 4 + kgrp) ^ (row & 7);
            short8 bfrag = *reinterpret_cast<const short8*>(&emb_s[row][kc * 8]);
            acc[c] = __builtin_amdgcn_mfma_f32_16x16x32_bf16(a, bfrag, acc[c], 0, 0, 0);
        }
    }
    {   // kk = 8: k in [256,288), all valid; B from global
        const int k0 = 256 + kgrp * 8;
        float4 f0 = *reinterpret_cast<const float4*>(xrow + k0);
        float4 f1 = *reinterpret_cast<const float4*>(xrow + k0 + 4);
        short8 a;
        a[0] = f2bf(f0.x); a[1] = f2bf(f0.y); a[2] = f2bf(f0.z); a[3] = f2bf(f0.w);
        a[4] = f2bf(f1.x); a[5] = f2bf(f1.y); a[6] = f2bf(f1.z); a[7] = f2bf(f1.w);
#pragma unroll
        for (int c = 0; c < 8; c++) {
            short8 bfrag = *reinterpret_cast<const short8*>(embT + (size_t)(c * 16 + lrow) * KPAD + k0);
            acc[c] = __builtin_amdgcn_mfma_f32_16x16x32_bf16(a, bfrag, acc[c], 0, 0, 0);
        }
    }
    {   // kk = 9: k in [288,320), mask k >= 300; B from global (zero-padded)
        const int k0 = 288 + kgrp * 8;
        short8 a;
#pragma unroll
        for (int j = 0; j < 8; j++) {
            int k = k0 + j;
            a[j] = f2bf((k < IN_DIM) ? xrow[k] : 0.0f);
        }
#pragma unroll
        for (int c = 0; c < 8; c++) {
            short8 bfrag = *reinterpret_cast<const short8*>(embT + (size_t)(c * 16 + lrow) * KPAD + k0);
            acc[c] = __builtin_amdgcn_mfma_f32_16x16x32_bf16(a, bfrag, acc[c], 0, 0, 0);
        }
    }

#pragma unroll
    for (int c = 0; c < 8; c++) {
        const int col = c * 16 + lrow;
        const float bias = b[col];
#pragma unroll
        for (int r = 0; r < 4; r++) {
            const int row = r0 + kgrp * 4 + r;
            if (row < N_NODES)
                h[(size_t)row * HID + col] = __float2bfloat16(fmaxf(acc[c][r] + bias, 0.0f));
        }
    }
}

// ---------------- gather-aggregate: quarter-wave per edge, 16B/lane, 4-deep ----------------
__global__ void k_gather(const int* __restrict__ rowend, const int* __restrict__ csr_src,
                         const bf16* __restrict__ h, const float* __restrict__ invdeg,
                         bf16* __restrict__ agg) {
    const int node = blockIdx.x * (blockDim.x >> 6) + (threadIdx.x >> 6);
    if (node >= N_NODES) return;
    const int lane = threadIdx.x & 63;
    const int g    = lane >> 4;
    const int fl   = lane & 15;
    const int beg = (node == 0) ? 0 : rowend[node - 1];
    const int end = rowend[node];

    float a0 = 0.f, a1 = 0.f, a2 = 0.f, a3 = 0.f;
    float a4 = 0.f, a5 = 0.f, a6 = 0.f, a7 = 0.f;
    float c0 = 0.f, c1 = 0.f, c2 = 0.f, c3 = 0.f;
    float c4 = 0.f, c5 = 0.f, c6 = 0.f, c7 = 0.f;

    int e = beg;
    for (; e + 16 <= end; e += 16) {        // 16 edges in flight per wave
        int s0 = csr_src[e + g];
        int s1 = csr_src[e + 4 + g];
        int s2 = csr_src[e + 8 + g];
        int s3 = csr_src[e + 12 + g];
        uint4 v0 = *reinterpret_cast<const uint4*>(h + (size_t)s0 * HID + fl * 8);
        uint4 v1 = *reinterpret_cast<const uint4*>(h + (size_t)s1 * HID + fl * 8);
        uint4 v2 = *reinterpret_cast<const uint4*>(h + (size_t)s2 * HID + fl * 8);
        uint4 v3 = *reinterpret_cast<const uint4*>(h + (size_t)s3 * HID + fl * 8);
        a0 += bflo(v0.x); a1 += bfhi(v0.x); a2 += bflo(v0.y); a3 += bfhi(v0.y);
        a4 += bflo(v0.z); a5 += bfhi(v0.z); a6 += bflo(v0.w); a7 += bfhi(v0.w);
        c0 += bflo(v1.x); c1 += bfhi(v1.x); c2 += bflo(v1.y); c3 += bfhi(v1.y);
        c4 += bflo(v1.z); c5 += bfhi(v1.z); c6 += bflo(v1.w); c7 += bfhi(v1.w);
        a0 += bflo(v2.x); a1 += bfhi(v2.x); a2 += bflo(v2.y); a3 += bfhi(v2.y);
        a4 += bflo(v2.z); a5 += bfhi(v2.z); a6 += bflo(v2.w); a7 += bfhi(v2.w);
        c0 += bflo(v3.x); c1 += bfhi(v3.x); c2 += bflo(v3.y); c3 += bfhi(v3.y);
        c4 += bflo(v3.z); c5 += bfhi(v3.z); c6 += bflo(v3.w); c7 += bfhi(v3.w);
    }
    for (; e + 8 <= end; e += 8) {
        int s0 = csr_src[e + g];
        int s1 = csr_src[e + 4 + g];
        uint4 v0 = *reinterpret_cast<const uint4*>(h + (size_t)s0 * HID + fl * 8);
        uint4 v1 = *reinterpret_cast<const uint4*>(h + (size_t)s1 * HID + fl * 8);
        a0 += bflo(v0.x); a1 += bfhi(v0.x); a2 += bflo(v0.y); a3 += bfhi(v0.y);
        a4 += bflo(v0.z); a5 += bfhi(v0.z); a6 += bflo(v0.w); a7 += bfhi(v0.w);
        c0 += bflo(v1.x); c1 += bfhi(v1.x); c2 += bflo(v1.y); c3 += bfhi(v1.y);
        c4 += bflo(v1.z); c5 += bfhi(v1.z); c6 += bflo(v1.w); c7 += bfhi(v1.w);
    }
    for (; e + 4 <= end; e += 4) {
        int s0 = csr_src[e + g];
        uint4 v0 = *reinterpret_cast<const uint4*>(h + (size_t)s0 * HID + fl * 8);
        a0 += bflo(v0.x); a1 += bfhi(v0.x); a2 += bflo(v0.y); a3 += bfhi(v0.y);
        a4 += bflo(v0.z); a5 += bfhi(v0.z); a6 += bflo(v0.w); a7 += bfhi(v0.w);
    }
    if (e < end) {                           // tail: 1..3 edges, per-group predicated
        int idx = e + g;
        bool valid = idx < end;
        int s = csr_src[valid ? idx : end - 1];
        uint4 v = *reinterpret_cast<const uint4*>(h + (size_t)s * HID + fl * 8);
        if (valid) {
            a0 += bflo(v.x); a1 += bfhi(v.x); a2 += bflo(v.y); a3 += bfhi(v.y);
            a4 += bflo(v.z); a5 += bfhi(v.z); a6 += bflo(v.w); a7 += bfhi(v.w);
        }
    }
    a0 += c0; a1 += c1; a2 += c2; a3 += c3;
    a4 += c4; a5 += c5; a6 += c6; a7 += c7;

    // reduce across the 4 groups (lanes differing in bits 4,5)
    a0 += __shfl_xor(a0, 16); a1 += __shfl_xor(a1, 16);
    a2 += __shfl_xor(a2, 16); a3 += __shfl_xor(a3, 16);
    a4 += __shfl_xor(a4, 16); a5 += __shfl_xor(a5, 16);
    a6 += __shfl_xor(a6, 16); a7 += __shfl_xor(a7, 16);
    a0 += __shfl_xor(a0, 32); a1 += __shfl_xor(a1, 32);
    a2 += __shfl_xor(a2, 32); a3 += __shfl_xor(a3, 32);
    a4 += __shfl_xor(a4, 32); a5 += __shfl_xor(a5, 32);
    a6 += __shfl_xor(a6, 32); a7 += __shfl_xor(a7, 32);

    if (g == 0) {
        const float id = invdeg[node];
        uint4 o;
        o.x = (unsigned)f2bfu(a0 * id) | ((unsigned)f2bfu(a1 * id) << 16);
        o.y = (unsigned)f2bfu(a2 * id) | ((unsigned)f2bfu(a3 * id) << 16);
        o.z = (unsigned)f2bfu(a4 * id) | ((unsigned)f2bfu(a5 * id) << 16);
        o.w = (unsigned)f2bfu(a6 * id) | ((unsigned)f2bfu(a7 * id) << 16);
        *reinterpret_cast<uint4*>(agg + (size_t)node * HID + fl * 8) = o;
    }
}

// ---------------- combine via MFMA with LDS-staged weights ----------------
// A-fragments (agg + h_in rows) issued into registers BEFORE staging + barrier,
// so their L2/L3 latency hides under the 64 KB weight staging.
// h_out may alias agg: each wave reads only its own 16 rows before writing them.
template<int STORE_F32>
__global__ __launch_bounds__(512)
void k_combine_mfma(const bf16* __restrict__ agg, const bf16* __restrict__ h_in,
                    const bf16* __restrict__ WlT, const bf16* __restrict__ WrT,
                    const float* __restrict__ bl, void* __restrict__ outp) {
    __shared__ bf16 wl_s[HID][HID];   // 32 KB, swizzled chunks
    __shared__ bf16 wr_s[HID][HID];   // 32 KB
    const int wid  = threadIdx.x >> 6;          // 0..7
    const int lane = threadIdx.x & 63;
    const int r0   = blockIdx.x * 128 + wid * 16;
    const int lrow = lane & 15;
    const int kgrp = lane >> 4;

    const int arow = min(r0 + lrow, N_NODES - 1);

    // ---- issue A-fragment loads early (latency hidden under staging) ----
    short8 aA[4], aH[4];
#pragma unroll
    for (int kk = 0; kk < 4; kk++) {
        const int k0 = kk * 32 + kgrp * 8;
        aA[kk] = *reinterpret_cast<const short8*>(agg  + (size_t)arow * HID + k0);
        aH[kk] = *reinterpret_cast<const short8*>(h_in + (size_t)arow * HID + k0);
    }

    // ---- stage weights: 128 rows x 16 chunks of 16B, swizzled ----
    for (int id = threadIdx.x; id < HID * 16; id += 512) {
        const int row = id >> 4, c16 = id & 15;
        const int sc  = c16 ^ (row & 7);
        *reinterpret_cast<uint4*>(&wl_s[row][sc * 8]) =
            *reinterpret_cast<const uint4*>(WlT + (size_t)row * HID + c16 * 8);
        *reinterpret_cast<uint4*>(&wr_s[row][sc * 8]) =
            *reinterpret_cast<const uint4*>(WrT + (size_t)row * HID + c16 * 8);
    }
    __syncthreads();

    f32x4 acc[8];
#pragma unroll
    for (int c = 0; c < 8; c++) acc[c] = (f32x4){0.f, 0.f, 0.f, 0.f};

#pragma unroll
    for (int kk = 0; kk < 4; kk++) {
#pragma unroll
        for (int c = 0; c < 8; c++) {
            const int row = c * 16 + lrow;
            const int kc  = (kk * 4 + kgrp) ^ (lrow & 7);
            short8 b = *reinterpret_cast<const short8*>(&wl_s[row][kc * 8]);
            acc[c] = __builtin_amdgcn_mfma_f32_16x16x32_bf16(aA[kk], b, acc[c], 0, 0, 0);
        }
    }
#pragma unroll
    for (int kk = 0; kk < 4; kk++) {
#pragma unroll
        for (int c = 0; c < 8; c++) {
            const int row = c * 16 + lrow;
            const int kc  = (kk * 4 + kgrp) ^ (lrow & 7);
            short8 b = *reinterpret_cast<const short8*>(&wr_s[row][kc * 8]);
            acc[c] = __builtin_amdgcn_mfma_f32_16x16x32_bf16(aH[kk], b, acc[c], 0, 0, 0);
        }
    }

#pragma unroll
    for (int c = 0; c < 8; c++) {
        const int col = c * 16 + lrow;
        const float bias = bl[col];
#pragma unroll
        for (int r = 0; r < 4; r++) {
            const int row = r0 + kgrp * 4 + r;
            if (row < N_NODES) {
                float v = fmaxf(acc[c][r] + bias, 0.0f);
                if (STORE_F32)
                    ((float*)outp)[(size_t)row * HID + col] = v;
                else
                    ((bf16*)outp)[(size_t)row * HID + col] = __float2bfloat16(v);
            }
        }
    }
}

extern "C" void kernel_launch(void* const* d_in, const int* in_sizes, int n_in,
                              void* d_out, int out_size, void* d_ws, size_t ws_size,
                              hipStream_t stream) {
    const float* x     = (const float*)d_in[0];
    const int*   ei    = (const int*)d_in[1];
    const float* emb_W = (const float*)d_in[2];
    const float* emb_b = (const float*)d_in[3];
    const float* Wl    = (const float*)d_in[4];
    const float* bl    = (const float*)d_in[5];
    const float* Wr    = (const float*)d_in[6];

    const int* src = ei;
    const int* dst = ei + N_EDGES;

    // workspace layout
    char* ws = (char*)d_ws;
    size_t o = 0;
    int*  degbuf = (int*)(ws + o);  o += ((size_t)N_NODES * 4 + 255) & ~(size_t)255;
    int*  rowcur = (int*)(ws + o);  o += ((size_t)N_NODES * 4 + 255) & ~(size_t)255;
    int*  csrsrc = (int*)(ws + o);  o += ((size_t)N_EDGES * 4 + 255) & ~(size_t)255;
    int*  bsum   = (int*)(ws + o);  o += ((size_t)NCH * 4 + 255) & ~(size_t)255;
    bf16* WlT    = (bf16*)(ws + o); o += ((size_t)NLAYERS * HID * HID * 2 + 255) & ~(size_t)255;
    bf16* WrT    = (bf16*)(ws + o); o += ((size_t)NLAYERS * HID * HID * 2 + 255) & ~(size_t)255;
    bf16* embT   = (bf16*)(ws + o); o += ((size_t)HID * KPAD * 2 + 255) & ~(size_t)255;
    bf16* bufA   = (bf16*)(ws + o); o += ((size_t)N_NODES * HID * 2 + 255) & ~(size_t)255;
    bf16* bufB   = (bf16*)(ws + o);

    // ---- build CSR ----
    hipMemsetAsync(degbuf, 0, (size_t)N_NODES * sizeof(int), stream);
    k_deg<<<(N_EDGES + 255) / 256, 256, 0, stream>>>(dst, degbuf);
    k_scan1<<<NCH, SB, 0, stream>>>(degbuf, bsum);
    k_scan3<<<NCH, SB, 0, stream>>>(degbuf, bsum, rowcur);
    const float* invdeg = (const float*)degbuf;
    k_fill<<<(N_EDGES + 255) / 256, 256, 0, stream>>>(src, dst, rowcur, csrsrc);
    // rowcur[n] is now the END offset of row n

    // ---- weight prep (fused) ----
    const int wtotal = NLAYERS * HID * HID + HID * KPAD;
    k_wprep<<<(wtotal + 255) / 256, 256, 0, stream>>>(Wl, Wr, emb_W, WlT, WrT, embT);

    // ---- h0 = relu(x @ emb_W + emb_b) -> bufA (bf16), via MFMA + 64KB LDS embT ----
    const int ngrid = (N_NODES + 3) / 4;      // 12500
    const int cgrid = (N_NODES + 127) / 128;  // 391
    k_embed_mfma<<<cgrid, 512, 0, stream>>>(x, embT, emb_b, bufA);

    for (int l = 0; l < NLAYERS; l++) {
        bf16* h_in = (l & 1) ? bufB : bufA;
        bf16* aggb = (l & 1) ? bufA : bufB;
        k_gather<<<ngrid, 256, 0, stream>>>(rowcur, csrsrc, h_in, invdeg, aggb);
        const bf16* wlt = WlT + (size_t)l * HID * HID;
        const bf16* wrt = WrT + (size_t)l * HID * HID;
        const float* blp = bl + (size_t)l * HID;
        if (l == NLAYERS - 1)
            k_combine_mfma<1><<<cgrid, 512, 0, stream>>>(aggb, h_in, wlt, wrt, blp, d_out);
        else
            k_combine_mfma<0><<<cgrid, 512, 0, stream>>>(aggb, h_in, wlt, wrt, blp, aggb);
    }
}

// Round 16
// 249.754 us; speedup vs baseline: 1.1628x; 1.0890x over previous
//
#include <hip/hip_runtime.h>
#include <hip/hip_bf16.h>

#define N_NODES 50000
#define N_EDGES 625000
#define IN_DIM  300
#define KPAD    320   // IN_DIM padded to multiple of 32
#define HID     128
#define NLAYERS 4

#define SB      256                            // scan block size
#define NCH     ((N_NODES + SB - 1) / SB)      // 196 chunks
#define EMBB    ((N_NODES + 127) / 128)        // 391 embed blocks
#define FILLB   ((N_EDGES + 511) / 512)        // 1221 fill blocks (512 thr)
#define DEGB    ((N_EDGES + 255) / 256)        // 2442 deg blocks
#define WTOTAL  (NLAYERS * HID * HID + HID * KPAD)
#define WPREPB  ((WTOTAL + 255) / 256)         // 416 wprep blocks

typedef __hip_bfloat16 bf16;
typedef __attribute__((ext_vector_type(8))) short short8;   // 8 bf16 = 4 VGPRs
typedef __attribute__((ext_vector_type(4))) float f32x4;

__device__ inline short f2bf(float v) {
    bf16 t = __float2bfloat16(v);
    return *reinterpret_cast<short*>(&t);
}
__device__ inline unsigned short f2bfu(float v) {
    bf16 t = __float2bfloat16(v);
    return *reinterpret_cast<unsigned short*>(&t);
}
__device__ inline float bflo(unsigned v) { return __uint_as_float((v & 0xffffu) << 16); }
__device__ inline float bfhi(unsigned v) { return __uint_as_float(v & 0xffff0000u); }

// ---------------- fused: degree histogram || weight prep ----------------
__global__ void k_deg_wprep(const int* __restrict__ dst, int* __restrict__ deg,
                            const float* __restrict__ Wl, const float* __restrict__ Wr,
                            const float* __restrict__ embW,
                            bf16* __restrict__ WlT, bf16* __restrict__ WrT,
                            bf16* __restrict__ embT) {
    if (blockIdx.x < DEGB) {
        int e = blockIdx.x * 256 + threadIdx.x;
        if (e < N_EDGES) atomicAdd(&deg[dst[e]], 1);
        return;
    }
    int idx = (blockIdx.x - DEGB) * 256 + threadIdx.x;
    const int total1 = NLAYERS * HID * HID;
    if (idx < total1) {
        int l = idx / (HID * HID);
        int rem = idx - l * HID * HID;
        int k = rem >> 7;
        int f = rem & 127;
        size_t o = (size_t)l * HID * HID + (size_t)f * HID + k;
        WlT[o] = __float2bfloat16(Wl[idx]);
        WrT[o] = __float2bfloat16(Wr[idx]);
        return;
    }
    int idx2 = idx - total1;
    if (idx2 < HID * KPAD) {
        int f = idx2 / KPAD, k = idx2 - f * KPAD;
        float v = (k < IN_DIM) ? embW[(size_t)k * HID + f] : 0.0f;
        embT[idx2] = __float2bfloat16(v);
    }
}

// ---------------- scan1: per-chunk sums ----------------
__global__ void k_scan1(const int* __restrict__ deg, int* __restrict__ bsum) {
    const int i = blockIdx.x * SB + threadIdx.x;
    int v = (i < N_NODES) ? deg[i] : 0;
#pragma unroll
    for (int off = 32; off > 0; off >>= 1) v += __shfl_down(v, off);
    __shared__ int wsum[SB / 64];
    if ((threadIdx.x & 63) == 0) wsum[threadIdx.x >> 6] = v;
    __syncthreads();
    if (threadIdx.x == 0) {
        int s = 0;
#pragma unroll
        for (int w = 0; w < SB / 64; w++) s += wsum[w];
        bsum[blockIdx.x] = s;
    }
}

// scan3: block-offset scan + within-chunk scan; deg -> invdeg in place
__global__ void k_scan3(int* __restrict__ degbuf, const int* __restrict__ bsum,
                        int* __restrict__ rowcur) {
    __shared__ int s[SB];
    __shared__ int bs[SB];
    const int b = blockIdx.x, t = threadIdx.x;

    int bv = (t < NCH) ? bsum[t] : 0;
    bs[t] = bv;
    __syncthreads();
    for (int off = 1; off < SB; off <<= 1) {
        int u = (t >= off) ? bs[t - off] : 0;
        __syncthreads();
        bs[t] += u;
        __syncthreads();
    }
    const int boff = (b == 0) ? 0 : bs[b - 1];

    const int i = b * SB + t;
    int v = (i < N_NODES) ? degbuf[i] : 0;
    s[t] = v;
    __syncthreads();
    for (int off = 1; off < SB; off <<= 1) {
        int u = (t >= off) ? s[t - off] : 0;
        __syncthreads();
        s[t] += u;
        __syncthreads();
    }
    if (i < N_NODES) {
        rowcur[i] = boff + s[t] - v;                     // exclusive prefix
        ((float*)degbuf)[i] = 1.0f / (float)max(v, 1);   // invdeg, in place
    }
}

// ---------------- fused: CSR fill || embedding MFMA ----------------
// blocks [0, EMBB): embed (512 thr, 64 KB LDS); blocks [EMBB, EMBB+FILLB): fill.
// Complementary bottlenecks (latency-bound vs atomic-bound) co-schedule.
__global__ __launch_bounds__(512)
void k_fill_embed(const int* __restrict__ src, const int* __restrict__ dst,
                  int* __restrict__ rowcur, int* __restrict__ csr_src,
                  const float* __restrict__ x, const bf16* __restrict__ embT,
                  const float* __restrict__ b, bf16* __restrict__ h) {
    __shared__ bf16 emb_s[HID][256];   // 64 KB

    if (blockIdx.x >= EMBB) {
        // ---- CSR fill part ----
        int e = (blockIdx.x - EMBB) * 512 + threadIdx.x;
        if (e < N_EDGES) {
            int d = dst[e];
            int pos = atomicAdd(&rowcur[d], 1);
            csr_src[pos] = src[e];
        }
        return;
    }

    // ---- embed part (round-11 body) ----
    const int wid  = threadIdx.x >> 6;          // 0..7
    const int lane = threadIdx.x & 63;
    const int r0   = blockIdx.x * 128 + wid * 16;
    const int lrow = lane & 15;
    const int kgrp = lane >> 4;

    for (int id = threadIdx.x; id < HID * 32; id += 512) {
        const int row = id >> 5, ch = id & 31;
        const int sc  = ch ^ (row & 7);
        *reinterpret_cast<uint4*>(&emb_s[row][sc * 8]) =
            *reinterpret_cast<const uint4*>(embT + (size_t)row * KPAD + ch * 8);
    }
    __syncthreads();

    const int arow = min(r0 + lrow, N_NODES - 1);
    const float* xrow = x + (size_t)arow * IN_DIM;

    f32x4 acc[8];
#pragma unroll
    for (int c = 0; c < 8; c++) acc[c] = (f32x4){0.f, 0.f, 0.f, 0.f};

#pragma unroll
    for (int kk = 0; kk < 8; kk++) {            // k < 256: B from LDS
        const int k0 = kk * 32 + kgrp * 8;
        float4 f0 = *reinterpret_cast<const float4*>(xrow + k0);
        float4 f1 = *reinterpret_cast<const float4*>(xrow + k0 + 4);
        short8 a;
        a[0] = f2bf(f0.x); a[1] = f2bf(f0.y); a[2] = f2bf(f0.z); a[3] = f2bf(f0.w);
        a[4] = f2bf(f1.x); a[5] = f2bf(f1.y); a[6] = f2bf(f1.z); a[7] = f2bf(f1.w);
#pragma unroll
        for (int c = 0; c < 8; c++) {
            const int row = c * 16 + lrow;
            const int kc  = (kk * 4 + kgrp) ^ (row & 7);
            short8 bfrag = *reinterpret_cast<const short8*>(&emb_s[row][kc * 8]);
            acc[c] = __builtin_amdgcn_mfma_f32_16x16x32_bf16(a, bfrag, acc[c], 0, 0, 0);
        }
    }
    {   // kk = 8: k in [256,288), all valid; B from global
        const int k0 = 256 + kgrp * 8;
        float4 f0 = *reinterpret_cast<const float4*>(xrow + k0);
        float4 f1 = *reinterpret_cast<const float4*>(xrow + k0 + 4);
        short8 a;
        a[0] = f2bf(f0.x); a[1] = f2bf(f0.y); a[2] = f2bf(f0.z); a[3] = f2bf(f0.w);
        a[4] = f2bf(f1.x); a[5] = f2bf(f1.y); a[6] = f2bf(f1.z); a[7] = f2bf(f1.w);
#pragma unroll
        for (int c = 0; c < 8; c++) {
            short8 bfrag = *reinterpret_cast<const short8*>(embT + (size_t)(c * 16 + lrow) * KPAD + k0);
            acc[c] = __builtin_amdgcn_mfma_f32_16x16x32_bf16(a, bfrag, acc[c], 0, 0, 0);
        }
    }
    {   // kk = 9: k in [288,320), mask k >= 300; B from global (zero-padded)
        const int k0 = 288 + kgrp * 8;
        short8 a;
#pragma unroll
        for (int j = 0; j < 8; j++) {
            int k = k0 + j;
            a[j] = f2bf((k < IN_DIM) ? xrow[k] : 0.0f);
        }
#pragma unroll
        for (int c = 0; c < 8; c++) {
            short8 bfrag = *reinterpret_cast<const short8*>(embT + (size_t)(c * 16 + lrow) * KPAD + k0);
            acc[c] = __builtin_amdgcn_mfma_f32_16x16x32_bf16(a, bfrag, acc[c], 0, 0, 0);
        }
    }

#pragma unroll
    for (int c = 0; c < 8; c++) {
        const int col = c * 16 + lrow;
        const float bias = b[col];
#pragma unroll
        for (int r = 0; r < 4; r++) {
            const int row = r0 + kgrp * 4 + r;
            if (row < N_NODES)
                h[(size_t)row * HID + col] = __float2bfloat16(fmaxf(acc[c][r] + bias, 0.0f));
        }
    }
}

// ---------------- gather-aggregate: quarter-wave per edge, 16B/lane, 4-deep ----------------
__global__ void k_gather(const int* __restrict__ rowend, const int* __restrict__ csr_src,
                         const bf16* __restrict__ h, const float* __restrict__ invdeg,
                         bf16* __restrict__ agg) {
    const int node = blockIdx.x * (blockDim.x >> 6) + (threadIdx.x >> 6);
    if (node >= N_NODES) return;
    const int lane = threadIdx.x & 63;
    const int g    = lane >> 4;
    const int fl   = lane & 15;
    const int beg = (node == 0) ? 0 : rowend[node - 1];
    const int end = rowend[node];

    float a0 = 0.f, a1 = 0.f, a2 = 0.f, a3 = 0.f;
    float a4 = 0.f, a5 = 0.f, a6 = 0.f, a7 = 0.f;
    float c0 = 0.f, c1 = 0.f, c2 = 0.f, c3 = 0.f;
    float c4 = 0.f, c5 = 0.f, c6 = 0.f, c7 = 0.f;

    int e = beg;
    for (; e + 16 <= end; e += 16) {        // 16 edges in flight per wave
        int s0 = csr_src[e + g];
        int s1 = csr_src[e + 4 + g];
        int s2 = csr_src[e + 8 + g];
        int s3 = csr_src[e + 12 + g];
        uint4 v0 = *reinterpret_cast<const uint4*>(h + (size_t)s0 * HID + fl * 8);
        uint4 v1 = *reinterpret_cast<const uint4*>(h + (size_t)s1 * HID + fl * 8);
        uint4 v2 = *reinterpret_cast<const uint4*>(h + (size_t)s2 * HID + fl * 8);
        uint4 v3 = *reinterpret_cast<const uint4*>(h + (size_t)s3 * HID + fl * 8);
        a0 += bflo(v0.x); a1 += bfhi(v0.x); a2 += bflo(v0.y); a3 += bfhi(v0.y);
        a4 += bflo(v0.z); a5 += bfhi(v0.z); a6 += bflo(v0.w); a7 += bfhi(v0.w);
        c0 += bflo(v1.x); c1 += bfhi(v1.x); c2 += bflo(v1.y); c3 += bfhi(v1.y);
        c4 += bflo(v1.z); c5 += bfhi(v1.z); c6 += bflo(v1.w); c7 += bfhi(v1.w);
        a0 += bflo(v2.x); a1 += bfhi(v2.x); a2 += bflo(v2.y); a3 += bfhi(v2.y);
        a4 += bflo(v2.z); a5 += bfhi(v2.z); a6 += bflo(v2.w); a7 += bfhi(v2.w);
        c0 += bflo(v3.x); c1 += bfhi(v3.x); c2 += bflo(v3.y); c3 += bfhi(v3.y);
        c4 += bflo(v3.z); c5 += bfhi(v3.z); c6 += bflo(v3.w); c7 += bfhi(v3.w);
    }
    for (; e + 8 <= end; e += 8) {
        int s0 = csr_src[e + g];
        int s1 = csr_src[e + 4 + g];
        uint4 v0 = *reinterpret_cast<const uint4*>(h + (size_t)s0 * HID + fl * 8);
        uint4 v1 = *reinterpret_cast<const uint4*>(h + (size_t)s1 * HID + fl * 8);
        a0 += bflo(v0.x); a1 += bfhi(v0.x); a2 += bflo(v0.y); a3 += bfhi(v0.y);
        a4 += bflo(v0.z); a5 += bfhi(v0.z); a6 += bflo(v0.w); a7 += bfhi(v0.w);
        c0 += bflo(v1.x); c1 += bfhi(v1.x); c2 += bflo(v1.y); c3 += bfhi(v1.y);
        c4 += bflo(v1.z); c5 += bfhi(v1.z); c6 += bflo(v1.w); c7 += bfhi(v1.w);
    }
    for (; e + 4 <= end; e += 4) {
        int s0 = csr_src[e + g];
        uint4 v0 = *reinterpret_cast<const uint4*>(h + (size_t)s0 * HID + fl * 8);
        a0 += bflo(v0.x); a1 += bfhi(v0.x); a2 += bflo(v0.y); a3 += bfhi(v0.y);
        a4 += bflo(v0.z); a5 += bfhi(v0.z); a6 += bflo(v0.w); a7 += bfhi(v0.w);
    }
    if (e < end) {                           // tail: 1..3 edges, per-group predicated
        int idx = e + g;
        bool valid = idx < end;
        int s = csr_src[valid ? idx : end - 1];
        uint4 v = *reinterpret_cast<const uint4*>(h + (size_t)s * HID + fl * 8);
        if (valid) {
            a0 += bflo(v.x); a1 += bfhi(v.x); a2 += bflo(v.y); a3 += bfhi(v.y);
            a4 += bflo(v.z); a5 += bfhi(v.z); a6 += bflo(v.w); a7 += bfhi(v.w);
        }
    }
    a0 += c0; a1 += c1; a2 += c2; a3 += c3;
    a4 += c4; a5 += c5; a6 += c6; a7 += c7;

    // reduce across the 4 groups (lanes differing in bits 4,5)
    a0 += __shfl_xor(a0, 16); a1 += __shfl_xor(a1, 16);
    a2 += __shfl_xor(a2, 16); a3 += __shfl_xor(a3, 16);
    a4 += __shfl_xor(a4, 16); a5 += __shfl_xor(a5, 16);
    a6 += __shfl_xor(a6, 16); a7 += __shfl_xor(a7, 16);
    a0 += __shfl_xor(a0, 32); a1 += __shfl_xor(a1, 32);
    a2 += __shfl_xor(a2, 32); a3 += __shfl_xor(a3, 32);
    a4 += __shfl_xor(a4, 32); a5 += __shfl_xor(a5, 32);
    a6 += __shfl_xor(a6, 32); a7 += __shfl_xor(a7, 32);

    if (g == 0) {
        const float id = invdeg[node];
        uint4 o;
        o.x = (unsigned)f2bfu(a0 * id) | ((unsigned)f2bfu(a1 * id) << 16);
        o.y = (unsigned)f2bfu(a2 * id) | ((unsigned)f2bfu(a3 * id) << 16);
        o.z = (unsigned)f2bfu(a4 * id) | ((unsigned)f2bfu(a5 * id) << 16);
        o.w = (unsigned)f2bfu(a6 * id) | ((unsigned)f2bfu(a7 * id) << 16);
        *reinterpret_cast<uint4*>(agg + (size_t)node * HID + fl * 8) = o;
    }
}

// ---------------- combine via MFMA with LDS-staged weights (round-11 form) ----------------
// h_out may alias agg: each wave reads only its own 16 rows before writing them.
template<int STORE_F32>
__global__ __launch_bounds__(512)
void k_combine_mfma(const bf16* __restrict__ agg, const bf16* __restrict__ h_in,
                    const bf16* __restrict__ WlT, const bf16* __restrict__ WrT,
                    const float* __restrict__ bl, void* __restrict__ outp) {
    __shared__ bf16 wl_s[HID][HID];   // 32 KB, swizzled chunks
    __shared__ bf16 wr_s[HID][HID];   // 32 KB
    const int wid  = threadIdx.x >> 6;          // 0..7
    const int lane = threadIdx.x & 63;
    const int r0   = blockIdx.x * 128 + wid * 16;
    const int lrow = lane & 15;
    const int kgrp = lane >> 4;

    for (int id = threadIdx.x; id < HID * 16; id += 512) {
        const int row = id >> 4, c16 = id & 15;
        const int sc  = c16 ^ (row & 7);
        *reinterpret_cast<uint4*>(&wl_s[row][sc * 8]) =
            *reinterpret_cast<const uint4*>(WlT + (size_t)row * HID + c16 * 8);
        *reinterpret_cast<uint4*>(&wr_s[row][sc * 8]) =
            *reinterpret_cast<const uint4*>(WrT + (size_t)row * HID + c16 * 8);
    }
    __syncthreads();

    f32x4 acc[8];
#pragma unroll
    for (int c = 0; c < 8; c++) acc[c] = (f32x4){0.f, 0.f, 0.f, 0.f};

    const int arow = min(r0 + lrow, N_NODES - 1);

#pragma unroll
    for (int kk = 0; kk < 4; kk++) {
        const int k0 = kk * 32 + kgrp * 8;
        short8 a = *reinterpret_cast<const short8*>(agg + (size_t)arow * HID + k0);
#pragma unroll
        for (int c = 0; c < 8; c++) {
            const int row = c * 16 + lrow;
            const int kc  = (kk * 4 + kgrp) ^ (lrow & 7);
            short8 b = *reinterpret_cast<const short8*>(&wl_s[row][kc * 8]);
            acc[c] = __builtin_amdgcn_mfma_f32_16x16x32_bf16(a, b, acc[c], 0, 0, 0);
        }
    }
#pragma unroll
    for (int kk = 0; kk < 4; kk++) {
        const int k0 = kk * 32 + kgrp * 8;
        short8 a = *reinterpret_cast<const short8*>(h_in + (size_t)arow * HID + k0);
#pragma unroll
        for (int c = 0; c < 8; c++) {
            const int row = c * 16 + lrow;
            const int kc  = (kk * 4 + kgrp) ^ (lrow & 7);
            short8 b = *reinterpret_cast<const short8*>(&wr_s[row][kc * 8]);
            acc[c] = __builtin_amdgcn_mfma_f32_16x16x32_bf16(a, b, acc[c], 0, 0, 0);
        }
    }

#pragma unroll
    for (int c = 0; c < 8; c++) {
        const int col = c * 16 + lrow;
        const float bias = bl[col];
#pragma unroll
        for (int r = 0; r < 4; r++) {
            const int row = r0 + kgrp * 4 + r;
            if (row < N_NODES) {
                float v = fmaxf(acc[c][r] + bias, 0.0f);
                if (STORE_F32)
                    ((float*)outp)[(size_t)row * HID + col] = v;
                else
                    ((bf16*)outp)[(size_t)row * HID + col] = __float2bfloat16(v);
            }
        }
    }
}

extern "C" void kernel_launch(void* const* d_in, const int* in_sizes, int n_in,
                              void* d_out, int out_size, void* d_ws, size_t ws_size,
                              hipStream_t stream) {
    const float* x     = (const float*)d_in[0];
    const int*   ei    = (const int*)d_in[1];
    const float* emb_W = (const float*)d_in[2];
    const float* emb_b = (const float*)d_in[3];
    const float* Wl    = (const float*)d_in[4];
    const float* bl    = (const float*)d_in[5];
    const float* Wr    = (const float*)d_in[6];

    const int* src = ei;
    const int* dst = ei + N_EDGES;

    // workspace layout
    char* ws = (char*)d_ws;
    size_t o = 0;
    int*  degbuf = (int*)(ws + o);  o += ((size_t)N_NODES * 4 + 255) & ~(size_t)255;
    int*  rowcur = (int*)(ws + o);  o += ((size_t)N_NODES * 4 + 255) & ~(size_t)255;
    int*  csrsrc = (int*)(ws + o);  o += ((size_t)N_EDGES * 4 + 255) & ~(size_t)255;
    int*  bsum   = (int*)(ws + o);  o += ((size_t)NCH * 4 + 255) & ~(size_t)255;
    bf16* WlT    = (bf16*)(ws + o); o += ((size_t)NLAYERS * HID * HID * 2 + 255) & ~(size_t)255;
    bf16* WrT    = (bf16*)(ws + o); o += ((size_t)NLAYERS * HID * HID * 2 + 255) & ~(size_t)255;
    bf16* embT   = (bf16*)(ws + o); o += ((size_t)HID * KPAD * 2 + 255) & ~(size_t)255;
    bf16* bufA   = (bf16*)(ws + o); o += ((size_t)N_NODES * HID * 2 + 255) & ~(size_t)255;
    bf16* bufB   = (bf16*)(ws + o);

    // ---- deg || wprep (independent, fused) ----
    hipMemsetAsync(degbuf, 0, (size_t)N_NODES * sizeof(int), stream);
    k_deg_wprep<<<DEGB + WPREPB, 256, 0, stream>>>(dst, degbuf, Wl, Wr, emb_W,
                                                   WlT, WrT, embT);
    k_scan1<<<NCH, SB, 0, stream>>>(degbuf, bsum);
    k_scan3<<<NCH, SB, 0, stream>>>(degbuf, bsum, rowcur);
    const float* invdeg = (const float*)degbuf;

    // ---- CSR fill || embed (independent, fused) ----
    k_fill_embed<<<EMBB + FILLB, 512, 0, stream>>>(src, dst, rowcur, csrsrc,
                                                   x, embT, emb_b, bufA);
    // rowcur[n] is now the END offset of row n

    const int ngrid = (N_NODES + 3) / 4;      // 12500
    const int cgrid = (N_NODES + 127) / 128;  // 391
    for (int l = 0; l < NLAYERS; l++) {
        bf16* h_in = (l & 1) ? bufB : bufA;
        bf16* aggb = (l & 1) ? bufA : bufB;
        k_gather<<<ngrid, 256, 0, stream>>>(rowcur, csrsrc, h_in, invdeg, aggb);
        const bf16* wlt = WlT + (size_t)l * HID * HID;
        const bf16* wrt = WrT + (size_t)l * HID * HID;
        const float* blp = bl + (size_t)l * HID;
        if (l == NLAYERS - 1)
            k_combine_mfma<1><<<cgrid, 512, 0, stream>>>(aggb, h_in, wlt, wrt, blp, d_out);
        else
            k_combine_mfma<0><<<cgrid, 512, 0, stream>>>(aggb, h_in, wlt, wrt, blp, aggb);
    }
}